// Round 1
// baseline (319.400 us; speedup 1.0000x reference)
//
#include <hip/hip_runtime.h>

#define Bb_ 4
#define Hh_ 16
#define Ss_ 1024
#define DH 64
#define MAXLEN 2048
#define BH (Bb_*Hh_)
#define LDST 72   // 64 + 8 pad (bf16 elems)
#define SW 132    // fp32 epilogue scratch stride (128 + 4 pad words, slow path)

typedef __attribute__((ext_vector_type(8))) short short8;
typedef __attribute__((ext_vector_type(4))) float floatx4;
typedef __attribute__((ext_vector_type(4))) unsigned short ushort4v;

static __device__ __forceinline__ unsigned short f2bf(float f) {
    unsigned int u = __builtin_bit_cast(unsigned int, f);
    u = (u + 0x7fffu + ((u >> 16) & 1u)) >> 16;   // RNE
    return (unsigned short)u;
}

// Stage a 128x64 fp32 tile (row stride 64) -> bf16 LDS tile (row stride LDST)
static __device__ __forceinline__ void stage_tile(unsigned short* lds,
                                                  const float* __restrict__ g,
                                                  int tid) {
#pragma unroll
    for (int it = 0; it < 8; ++it) {
        int idx = it * 1024 + tid * 4;
        int row = idx >> 6, col = idx & 63;
        const float4 v = *reinterpret_cast<const float4*>(g + row * 64 + col);
        ushort4v o = { f2bf(v.x), f2bf(v.y), f2bf(v.z), f2bf(v.w) };
        *reinterpret_cast<ushort4v*>(lds + row * LDST + col) = o;
    }
}

// R14: (1) early-exit phase 1 — ctx terms g*t are all nonnegative, so once
// every row's PARTIAL sum >= clip bound, ctx clips to MAXLEN-2 regardless of
// the remaining tiles. Process t-tiles top-down; the top tile (t in
// [896,1024)) contributes ~61k >> 2046 for typical rows, so one tile + a
// block vote replaces eight. Threshold 4096 gives ~18-sigma margin over
// bf16 partial-sum error; failing rows fall through to the exact path.
// (2) fast-path emit: all 1024 row-dots computed once into LDS, then one
// unbroken 128-iteration NT-store stream with ZERO barriers (the old per-mt
// structure drained vmcnt(0) at 16 barriers, chopping store BW).
__global__ __launch_bounds__(256, 2)
void cope_kernel(const float* __restrict__ q, const float* __restrict__ k,
                 const float* __restrict__ tb, float* __restrict__ out) {
    __shared__ __align__(16) unsigned char smem[73728];
    __shared__ float sh_ctx[128];
    __shared__ float sh_sc[128];
    __shared__ float2 sh_mm;
    __shared__ int shf[4];

    unsigned short* Ab = reinterpret_cast<unsigned short*>(smem);
    unsigned short* Kb0 = reinterpret_cast<unsigned short*>(smem + 18432);
    float* scratch = reinterpret_cast<float*>(smem + 18432);
    unsigned short* Pb = reinterpret_cast<unsigned short*>(smem + 55296);
    float* pr = sh_sc;                                   // fp32 emb row cache
    float* sdots = reinterpret_cast<float*>(smem);       // fast path: 1024 row consts (reuses Ab)

    int bx = blockIdx.x;
    // swizzle: blocks sharing this bh's k/q-stream are 64 apart -> same XCD
    int bh = bx & 63, nt = bx >> 6;
    int n0 = nt << 7;
    int tid = threadIdx.x;
    int lane = tid & 63, w = tid >> 6;
    int lo = lane & 15, quad = lane >> 4;

    const float* kb = k + (size_t)bh * Ss_ * DH;
    const float* qb = q + (size_t)bh * Ss_ * DH;

    // ---------------- Phase 1: ctx for rows n0..n0+127 (top tile first) ----
    stage_tile(Ab, qb + (size_t)n0 * DH, tid);
    stage_tile(Kb0, kb + (size_t)7 * 128 * DH, tid);
    __syncthreads();

    short8 afr[2][2];
#pragma unroll
    for (int i = 0; i < 2; ++i)
#pragma unroll
        for (int k2 = 0; k2 < 2; ++k2)
            afr[i][k2] = *reinterpret_cast<const short8*>(
                &Ab[(w * 32 + i * 16 + lo) * LDST + k2 * 32 + quad * 8]);

    float rp[2][4];
#pragma unroll
    for (int i = 0; i < 2; ++i)
#pragma unroll
        for (int r = 0; r < 4; ++r) rp[i][r] = 0.f;

    const float kSig = -0.18033688011112042f;  // -(1/8)*log2(e)

    auto compute_tile = [&](const unsigned short* cur, int t0) {
#pragma unroll
        for (int j = 0; j < 8; ++j) {
            short8 b0 = *reinterpret_cast<const short8*>(
                &cur[(j * 16 + lo) * LDST + 0 + quad * 8]);
            short8 b1 = *reinterpret_cast<const short8*>(
                &cur[(j * 16 + lo) * LDST + 32 + quad * 8]);
            float tcol = (float)(t0 + j * 16 + lo);
#pragma unroll
            for (int i = 0; i < 2; ++i) {
                floatx4 c = {0.f, 0.f, 0.f, 0.f};
                c = __builtin_amdgcn_mfma_f32_16x16x32_bf16(afr[i][0], b0, c, 0, 0, 0);
                c = __builtin_amdgcn_mfma_f32_16x16x32_bf16(afr[i][1], b1, c, 0, 0, 0);
#pragma unroll
                for (int r = 0; r < 4; ++r) {
                    float e = __builtin_amdgcn_exp2f(c[r] * kSig);
                    float g = __builtin_amdgcn_rcpf(1.0f + e);
                    rp[i][r] = fmaf(g, tcol, rp[i][r]);
                }
            }
        }
    };

    compute_tile(Kb0, 7 << 7);

    // Early-exit vote: every row's partial already past the clip bound?
    bool ok = true;
#pragma unroll
    for (int i = 0; i < 2; ++i)
#pragma unroll
        for (int r = 0; r < 4; ++r) {
            float v = rp[i][r];
            v += __shfl_xor(v, 1);
            v += __shfl_xor(v, 2);
            v += __shfl_xor(v, 4);
            v += __shfl_xor(v, 8);
            ok = ok && (v >= 4096.0f);   // margin over 2046 vs bf16 error
        }
    int wall = __all(ok);
    if (lane == 0) shf[w] = wall;
    __syncthreads();

    bool fast;
    float fastv;
    if (shf[0] & shf[1] & shf[2] & shf[3]) {
        fast = true;
        fastv = (float)(MAXLEN - 2);     // all rows clip exactly
    } else {
        // -------- rare exact path: finish tiles 6..0 (single-buffered) -----
        for (int tt = 6; tt >= 0; --tt) {
            stage_tile(Kb0, kb + (size_t)tt * 128 * DH, tid);
            __syncthreads();
            compute_tile(Kb0, tt << 7);
            __syncthreads();
        }
#pragma unroll
        for (int i = 0; i < 2; ++i)
#pragma unroll
            for (int r = 0; r < 4; ++r) {
                float v = rp[i][r];
                v += __shfl_xor(v, 1);
                v += __shfl_xor(v, 2);
                v += __shfl_xor(v, 4);
                v += __shfl_xor(v, 8);
                if (lo == 0) {
                    int lr = w * 32 + i * 16 + quad * 4 + r;
                    sh_ctx[lr] = fminf(fmaxf(v, 0.f), (float)(MAXLEN - 2));
                }
            }
        __syncthreads();

        if (tid < 64) {
            float a = sh_ctx[tid], b = sh_ctx[tid + 64];
            float mn = fminf(a, b), mx = fmaxf(a, b);
#pragma unroll
            for (int off = 1; off < 64; off <<= 1) {
                mn = fminf(mn, __shfl_xor(mn, off));
                mx = fmaxf(mx, __shfl_xor(mx, off));
            }
            if (tid == 0) sh_mm = make_float2(mn, mx);
        }
        __syncthreads();
        float2 mmv = sh_mm;
        fast = (mmv.x == mmv.y);
        fastv = mmv.x;
    }

    if (fast) {
        // ------- FAST PATH: row-constant strip; one unbroken store stream --
        float v = fastv;
        int fl = (int)v;
        float fr = v - (float)fl;
        int ce = min(fl + 1, MAXLEN - 1);
        if (tid < 16) {
            int d0 = tid * 4;
            const float4 e0 = *reinterpret_cast<const float4*>(tb + fl * DH + d0);
            const float4 e1 = *reinterpret_cast<const float4*>(tb + ce * DH + d0);
            pr[d0 + 0] = e0.x + fr * (e1.x - e0.x);
            pr[d0 + 1] = e0.y + fr * (e1.y - e0.y);
            pr[d0 + 2] = e0.z + fr * (e1.z - e0.z);
            pr[d0 + 3] = e0.w + fr * (e1.w - e0.w);
        }
        __syncthreads();

        // emb half-row in registers (2 threads per q-row)
        float ph[32];
        int half = tid & 1;
#pragma unroll
        for (int d = 0; d < 32; ++d) ph[d] = pr[half * 32 + d];

        // all 1024 row-dots up front (8 passes x 128 rows)
#pragma unroll 2
        for (int pass = 0; pass < 8; ++pass) {
            int row = pass * 128 + (tid >> 1);
            const float* qr = qb + (size_t)row * DH + half * 32;
            float s = 0.f;
#pragma unroll
            for (int d = 0; d < 32; d += 4) {
                const float4 qq = *reinterpret_cast<const float4*>(qr + d);
                s += qq.x * ph[d] + qq.y * ph[d + 1] + qq.z * ph[d + 2] +
                     qq.w * ph[d + 3];
            }
            s += __shfl_xor(s, 1);
            if (half == 0) sdots[row] = s;
        }
        __syncthreads();

        // Stream the whole 1024x128 strip: 128 NT stores/thread, NO barriers.
        // wave = 2 rows x 512B contiguous segments; full lines.
        float* po = out + (size_t)bh * Ss_ * Ss_ + n0 +
                    (size_t)(tid >> 5) * Ss_ + (tid & 31) * 4;
        const float* sd = sdots + (tid >> 5);
#pragma unroll 16
        for (int it = 0; it < 128; ++it) {
            float c = sd[it * 8];
            floatx4 vv = {c, c, c, c};
            __builtin_nontemporal_store(
                vv, reinterpret_cast<floatx4*>(po + (size_t)it * 8 * Ss_));
        }
        return;
    }

    // ------- SLOW PATH: build Pb, then 8 m-tiles of MFMA GEMM -------
    {
        int rsub = tid >> 4;       // 0..15
        int d0 = (tid & 15) * 4;   // 0..60
#pragma unroll
        for (int pass = 0; pass < 8; ++pass) {
            int row = pass * 16 + rsub;
            float c = sh_ctx[row];
            int fl = (int)c;
            float fr = c - (float)fl;
            int ce = min(fl + 1, MAXLEN - 1);
            const float4 e0 = *reinterpret_cast<const float4*>(tb + fl * DH + d0);
            const float4 e1 = *reinterpret_cast<const float4*>(tb + ce * DH + d0);
            ushort4v o = { f2bf(e0.x + fr * (e1.x - e0.x)),
                           f2bf(e0.y + fr * (e1.y - e0.y)),
                           f2bf(e0.z + fr * (e1.z - e0.z)),
                           f2bf(e0.w + fr * (e1.w - e0.w)) };
            *reinterpret_cast<ushort4v*>(&Pb[row * LDST + d0]) = o;
        }
    }
    __syncthreads();

    // B-fragments are loop-invariant across m-tiles: hoist to registers
    short8 bfr[8][2];
#pragma unroll
    for (int j = 0; j < 8; ++j) {
        bfr[j][0] = *reinterpret_cast<const short8*>(
            &Pb[(j * 16 + lo) * LDST + 0 + quad * 8]);
        bfr[j][1] = *reinterpret_cast<const short8*>(
            &Pb[(j * 16 + lo) * LDST + 32 + quad * 8]);
    }

#pragma unroll 1
    for (int mt = 0; mt < 8; ++mt) {
        int m0 = mt << 7;
        stage_tile(Ab, qb + (size_t)m0 * DH, tid);
        __syncthreads();

        short8 mfr[2][2];
#pragma unroll
        for (int i = 0; i < 2; ++i)
#pragma unroll
            for (int k2 = 0; k2 < 2; ++k2)
                mfr[i][k2] = *reinterpret_cast<const short8*>(
                    &Ab[(w * 32 + i * 16 + lo) * LDST + k2 * 32 + quad * 8]);

        floatx4 acc[2][8];
#pragma unroll
        for (int i = 0; i < 2; ++i)
#pragma unroll
            for (int j = 0; j < 8; ++j) acc[i][j] = (floatx4){0.f, 0.f, 0.f, 0.f};

#pragma unroll
        for (int j = 0; j < 8; ++j)
#pragma unroll
            for (int i = 0; i < 2; ++i) {
                acc[i][j] = __builtin_amdgcn_mfma_f32_16x16x32_bf16(
                    mfr[i][0], bfr[j][0], acc[i][j], 0, 0, 0);
                acc[i][j] = __builtin_amdgcn_mfma_f32_16x16x32_bf16(
                    mfr[i][1], bfr[j][1], acc[i][j], 0, 0, 0);
            }

        // Epilogue: LDS transpose -> contiguous dwordx4 NT stores
#pragma unroll
        for (int i = 0; i < 2; ++i) {
            __syncthreads();
#pragma unroll
            for (int j = 0; j < 8; ++j)
#pragma unroll
                for (int r = 0; r < 4; ++r) {
                    int lrow = w * 16 + quad * 4 + r;
                    scratch[lrow * SW + j * 16 + lo] = acc[i][j][r];
                }
            __syncthreads();
#pragma unroll
            for (int it = 0; it < 8; ++it) {
                int flat = it * 1024 + tid * 4;
                int lrow = flat >> 7, col = flat & 127;
                floatx4 vv =
                    *reinterpret_cast<const floatx4*>(&scratch[lrow * SW + col]);
                int grow = m0 + (lrow >> 4) * 32 + i * 16 + (lrow & 15);
                __builtin_nontemporal_store(
                    vv, reinterpret_cast<floatx4*>(
                            out + (size_t)(bh * Ss_ + grow) * Ss_ + n0 + col));
            }
        }
        __syncthreads();  // scratch/Ab safe for next mt
    }
}

extern "C" void kernel_launch(void* const* d_in, const int* in_sizes, int n_in,
                              void* d_out, int out_size, void* d_ws, size_t ws_size,
                              hipStream_t stream) {
    const float* q  = (const float*)d_in[0];
    const float* k  = (const float*)d_in[1];
    const float* tb = (const float*)d_in[2];
    float* out = (float*)d_out;

    cope_kernel<<<BH * 8, 256, 0, stream>>>(q, k, tb, out);
}

// Round 2
// 308.832 us; speedup vs baseline: 1.0342x; 1.0342x over previous
//
#include <hip/hip_runtime.h>

#define Bb_ 4
#define Hh_ 16
#define Ss_ 1024
#define DH 64
#define MAXLEN 2048
#define BH (Bb_*Hh_)
#define LDST 72   // 64 + 8 pad (bf16 elems)
#define SW 132    // fp32 epilogue scratch stride (128 + 4 pad words, slow path)

typedef __attribute__((ext_vector_type(8))) short short8;
typedef __attribute__((ext_vector_type(4))) float floatx4;
typedef __attribute__((ext_vector_type(4))) unsigned short ushort4v;

static __device__ __forceinline__ unsigned short f2bf(float f) {
    unsigned int u = __builtin_bit_cast(unsigned int, f);
    u = (u + 0x7fffu + ((u >> 16) & 1u)) >> 16;   // RNE
    return (unsigned short)u;
}

// Stage a 128x64 fp32 tile (row stride 64) -> bf16 LDS tile (row stride LDST)
static __device__ __forceinline__ void stage_tile(unsigned short* lds,
                                                  const float* __restrict__ g,
                                                  int tid) {
#pragma unroll
    for (int it = 0; it < 8; ++it) {
        int idx = it * 1024 + tid * 4;
        int row = idx >> 6, col = idx & 63;
        const float4 v = *reinterpret_cast<const float4*>(g + row * 64 + col);
        ushort4v o = { f2bf(v.x), f2bf(v.y), f2bf(v.z), f2bf(v.w) };
        *reinterpret_cast<ushort4v*>(lds + row * LDST + col) = o;
    }
}

// R15: transpose the output decomposition. R11/R13/R14 all plateaued at
// ~148 us kernel regardless of store SCHEDULING -> the limit is the store
// ADDRESS pattern (512B segments, 4KB row stride, 4MB footprint per block
// => DRAM page thrash at ~2 TB/s). Block (bh,st) now owns output ROWS
// [s0,s0+128) x all 1024 cols = contiguous 512KB; each iteration writes one
// full 4KB row (1KB/wave-inst, sequential addresses). Enabled by a cheap
// global vote: all 1024 t clip iff every row's partial over 32 top k-cols
// (t' in [992,1024)) >= 4096 (expected ~16k, ~10 sigma; failure falls to an
// exact slow path, so the threshold is perf-only, not correctness). All 8
// blocks of a bh compute the vote bitwise-identically -> consistent branch.
__global__ __launch_bounds__(256, 2)
void cope_kernel(const float* __restrict__ q, const float* __restrict__ k,
                 const float* __restrict__ tb, float* __restrict__ out) {
    __shared__ __align__(16) unsigned char smem[73728];
    __shared__ __align__(16) float sh_c[128];
    __shared__ __align__(16) float sh_pr[64];
    __shared__ int shf[4];
    __shared__ __align__(16) float ctx_all[1024];  // slow path only

    unsigned short* Ab = reinterpret_cast<unsigned short*>(smem);          // q tile
    unsigned short* Kb = reinterpret_cast<unsigned short*>(smem + 18432);  // 32-row vote k-tile
    float* scratch = reinterpret_cast<float*>(smem + 18432);               // slow epilogue (33792 B)
    unsigned short* Pb = reinterpret_cast<unsigned short*>(smem + 55296);  // slow: k tiles / emb tiles

    int bx = blockIdx.x;
    // blocks sharing this bh's q/k stream are 64 apart -> same XCD
    int bh = bx & 63, st = bx >> 6;
    int s0 = st << 7;
    int tid = threadIdx.x;
    int lane = tid & 63, w = tid >> 6;
    int lo = lane & 15, quad = lane >> 4;

    const float* kb = k + (size_t)bh * Ss_ * DH;
    const float* qb = q + (size_t)bh * Ss_ * DH;

    const float kSig = -0.18033688011112042f;  // -(1/8)*log2(e)

    // ---------------- Phase 1: global clip vote over ALL 1024 t ----------
    {   // stage k rows [992,1024) -> Kb (32 x 64)
        const float* ktop = kb + (size_t)992 * DH;
#pragma unroll
        for (int it = 0; it < 2; ++it) {
            int idx = it * 1024 + tid * 4;
            int row = idx >> 6, col = idx & 63;
            const float4 v = *reinterpret_cast<const float4*>(ktop + row * 64 + col);
            ushort4v o = { f2bf(v.x), f2bf(v.y), f2bf(v.z), f2bf(v.w) };
            *reinterpret_cast<ushort4v*>(Kb + row * LDST + col) = o;
        }
    }

    bool ok = true;
    short8 bkr[2][2];
#pragma unroll 1
    for (int qt = 0; qt < 8; ++qt) {
        stage_tile(Ab, qb + (size_t)qt * 128 * DH, tid);
        __syncthreads();
        if (qt == 0) {
#pragma unroll
            for (int j = 0; j < 2; ++j) {
                bkr[j][0] = *reinterpret_cast<const short8*>(
                    &Kb[(j * 16 + lo) * LDST + 0 + quad * 8]);
                bkr[j][1] = *reinterpret_cast<const short8*>(
                    &Kb[(j * 16 + lo) * LDST + 32 + quad * 8]);
            }
        }
        short8 afr[2][2];
#pragma unroll
        for (int i = 0; i < 2; ++i)
#pragma unroll
            for (int k2 = 0; k2 < 2; ++k2)
                afr[i][k2] = *reinterpret_cast<const short8*>(
                    &Ab[(w * 32 + i * 16 + lo) * LDST + k2 * 32 + quad * 8]);

        float ps[2][4];
#pragma unroll
        for (int i = 0; i < 2; ++i)
#pragma unroll
            for (int r = 0; r < 4; ++r) ps[i][r] = 0.f;

#pragma unroll
        for (int j = 0; j < 2; ++j) {
            float tcol = (float)(992 + j * 16 + lo);
#pragma unroll
            for (int i = 0; i < 2; ++i) {
                floatx4 c = {0.f, 0.f, 0.f, 0.f};
                c = __builtin_amdgcn_mfma_f32_16x16x32_bf16(afr[i][0], bkr[j][0], c, 0, 0, 0);
                c = __builtin_amdgcn_mfma_f32_16x16x32_bf16(afr[i][1], bkr[j][1], c, 0, 0, 0);
#pragma unroll
                for (int r = 0; r < 4; ++r) {
                    float e = __builtin_amdgcn_exp2f(c[r] * kSig);
                    float g = __builtin_amdgcn_rcpf(1.0f + e);
                    ps[i][r] = fmaf(g, tcol, ps[i][r]);
                }
            }
        }
#pragma unroll
        for (int i = 0; i < 2; ++i)
#pragma unroll
            for (int r = 0; r < 4; ++r) {
                float v = ps[i][r];
                v += __shfl_xor(v, 1);
                v += __shfl_xor(v, 2);
                v += __shfl_xor(v, 4);
                v += __shfl_xor(v, 8);
                ok = ok && (v >= 4096.0f);
            }
        __syncthreads();
    }

    int wall = __all(ok);
    if (lane == 0) shf[w] = wall;
    __syncthreads();

    if (shf[0] & shf[1] & shf[2] & shf[3]) {
        // ------- FAST PATH: every ctx clips to 2046 exactly (fr = 0) ------
        if (tid < 16) {
            int d0 = tid * 4;
            *reinterpret_cast<float4*>(&sh_pr[d0]) =
                *reinterpret_cast<const float4*>(tb + (size_t)(MAXLEN - 2) * DH + d0);
        }
        __syncthreads();

        // 128 row-dots: 2 threads per row
        int half = tid & 1;
        float ph[32];
#pragma unroll
        for (int d = 0; d < 32; ++d) ph[d] = sh_pr[half * 32 + d];
        {
            int row = tid >> 1;
            const float* qr = qb + (size_t)(s0 + row) * DH + half * 32;
            float s = 0.f;
#pragma unroll
            for (int d = 0; d < 32; d += 4) {
                const float4 qq = *reinterpret_cast<const float4*>(qr + d);
                s += qq.x * ph[d] + qq.y * ph[d + 1] + qq.z * ph[d + 2] +
                     qq.w * ph[d + 3];
            }
            s += __shfl_xor(s, 1);
            if (half == 0) sh_c[row] = s;
        }
        __syncthreads();

        // Contiguous 512 KB stream: iteration it = one full 4KB output row.
        float* po = out + (size_t)bh * (Ss_ * Ss_) + (size_t)s0 * Ss_ + tid * 4;
#pragma unroll 8
        for (int it = 0; it < 128; ++it) {
            float c = sh_c[it];
            floatx4 vv = {c, c, c, c};
            __builtin_nontemporal_store(
                vv, reinterpret_cast<floatx4*>(po + it * Ss_));
        }
        return;
    }

    // ================= SLOW PATH (exact; not taken on bench data) =========
    // 1) exact ctx for ALL 1024 t-rows
#pragma unroll 1
    for (int qt = 0; qt < 8; ++qt) {
        stage_tile(Ab, qb + (size_t)qt * 128 * DH, tid);
        float rp2[2][4];
#pragma unroll
        for (int i = 0; i < 2; ++i)
#pragma unroll
            for (int r = 0; r < 4; ++r) rp2[i][r] = 0.f;
        short8 afr[2][2];
#pragma unroll 1
        for (int kt = 0; kt < 8; ++kt) {
            stage_tile(Pb, kb + (size_t)kt * 128 * DH, tid);
            __syncthreads();
            if (kt == 0) {
#pragma unroll
                for (int i = 0; i < 2; ++i)
#pragma unroll
                    for (int k2 = 0; k2 < 2; ++k2)
                        afr[i][k2] = *reinterpret_cast<const short8*>(
                            &Ab[(w * 32 + i * 16 + lo) * LDST + k2 * 32 + quad * 8]);
            }
            int t0 = kt << 7;
#pragma unroll
            for (int j = 0; j < 8; ++j) {
                short8 b0 = *reinterpret_cast<const short8*>(
                    &Pb[(j * 16 + lo) * LDST + 0 + quad * 8]);
                short8 b1 = *reinterpret_cast<const short8*>(
                    &Pb[(j * 16 + lo) * LDST + 32 + quad * 8]);
                float tcol = (float)(t0 + j * 16 + lo);
#pragma unroll
                for (int i = 0; i < 2; ++i) {
                    floatx4 c = {0.f, 0.f, 0.f, 0.f};
                    c = __builtin_amdgcn_mfma_f32_16x16x32_bf16(afr[i][0], b0, c, 0, 0, 0);
                    c = __builtin_amdgcn_mfma_f32_16x16x32_bf16(afr[i][1], b1, c, 0, 0, 0);
#pragma unroll
                    for (int r = 0; r < 4; ++r) {
                        float e = __builtin_amdgcn_exp2f(c[r] * kSig);
                        float g = __builtin_amdgcn_rcpf(1.0f + e);
                        rp2[i][r] = fmaf(g, tcol, rp2[i][r]);
                    }
                }
            }
            __syncthreads();
        }
#pragma unroll
        for (int i = 0; i < 2; ++i)
#pragma unroll
            for (int r = 0; r < 4; ++r) {
                float v = rp2[i][r];
                v += __shfl_xor(v, 1);
                v += __shfl_xor(v, 2);
                v += __shfl_xor(v, 4);
                v += __shfl_xor(v, 8);
                if (lo == 0) {
                    int lr = qt * 128 + w * 32 + i * 16 + quad * 4 + r;
                    ctx_all[lr] = fminf(fmaxf(v, 0.f), (float)(MAXLEN - 2));
                }
            }
    }
    __syncthreads();

    // 2) GEMM: out rows [s0,s0+128) x all 1024 cols, emb tiles of 128
    stage_tile(Ab, qb + (size_t)s0 * DH, tid);
    __syncthreads();
    short8 mfr[2][2];
#pragma unroll
    for (int i = 0; i < 2; ++i)
#pragma unroll
        for (int k2 = 0; k2 < 2; ++k2)
            mfr[i][k2] = *reinterpret_cast<const short8*>(
                &Ab[(w * 32 + i * 16 + lo) * LDST + k2 * 32 + quad * 8]);

#pragma unroll 1
    for (int kt = 0; kt < 8; ++kt) {
        {   // build 128-row emb tile for t = kt*128 + row
            int rsub = tid >> 4;       // 0..15
            int d0 = (tid & 15) * 4;   // 0..60
#pragma unroll
            for (int pass = 0; pass < 8; ++pass) {
                int row = pass * 16 + rsub;
                float c = ctx_all[kt * 128 + row];
                int fl = (int)c;
                float fr = c - (float)fl;
                int ce = min(fl + 1, MAXLEN - 1);
                const float4 e0 = *reinterpret_cast<const float4*>(tb + fl * DH + d0);
                const float4 e1 = *reinterpret_cast<const float4*>(tb + ce * DH + d0);
                ushort4v o = { f2bf(e0.x + fr * (e1.x - e0.x)),
                               f2bf(e0.y + fr * (e1.y - e0.y)),
                               f2bf(e0.z + fr * (e1.z - e0.z)),
                               f2bf(e0.w + fr * (e1.w - e0.w)) };
                *reinterpret_cast<ushort4v*>(&Pb[row * LDST + d0]) = o;
            }
        }
        __syncthreads();

        short8 bfr[8][2];
#pragma unroll
        for (int j = 0; j < 8; ++j) {
            bfr[j][0] = *reinterpret_cast<const short8*>(
                &Pb[(j * 16 + lo) * LDST + 0 + quad * 8]);
            bfr[j][1] = *reinterpret_cast<const short8*>(
                &Pb[(j * 16 + lo) * LDST + 32 + quad * 8]);
        }

        floatx4 acc[2][8];
#pragma unroll
        for (int i = 0; i < 2; ++i)
#pragma unroll
            for (int j = 0; j < 8; ++j) acc[i][j] = (floatx4){0.f, 0.f, 0.f, 0.f};

#pragma unroll
        for (int j = 0; j < 8; ++j)
#pragma unroll
            for (int i = 0; i < 2; ++i) {
                acc[i][j] = __builtin_amdgcn_mfma_f32_16x16x32_bf16(
                    mfr[i][0], bfr[j][0], acc[i][j], 0, 0, 0);
                acc[i][j] = __builtin_amdgcn_mfma_f32_16x16x32_bf16(
                    mfr[i][1], bfr[j][1], acc[i][j], 0, 0, 0);
            }

        // Epilogue: LDS transpose -> contiguous dwordx4 NT stores
#pragma unroll
        for (int i = 0; i < 2; ++i) {
            __syncthreads();
#pragma unroll
            for (int j = 0; j < 8; ++j)
#pragma unroll
                for (int r = 0; r < 4; ++r) {
                    int lrow = w * 16 + quad * 4 + r;
                    scratch[lrow * SW + j * 16 + lo] = acc[i][j][r];
                }
            __syncthreads();
#pragma unroll
            for (int it = 0; it < 8; ++it) {
                int flat = it * 1024 + tid * 4;
                int lrow = flat >> 7, col = flat & 127;
                floatx4 vv =
                    *reinterpret_cast<const floatx4*>(&scratch[lrow * SW + col]);
                int grow = (lrow >> 4) * 32 + i * 16 + (lrow & 15);
                __builtin_nontemporal_store(
                    vv, reinterpret_cast<floatx4*>(
                            out + (size_t)(bh * Ss_ + s0 + grow) * Ss_ + kt * 128 + col));
            }
        }
        __syncthreads();  // Pb/scratch safe for next kt
    }
}

extern "C" void kernel_launch(void* const* d_in, const int* in_sizes, int n_in,
                              void* d_out, int out_size, void* d_ws, size_t ws_size,
                              hipStream_t stream) {
    const float* q  = (const float*)d_in[0];
    const float* k  = (const float*)d_in[1];
    const float* tb = (const float*)d_in[2];
    float* out = (float*)d_out;

    cope_kernel<<<BH * 8, 256, 0, stream>>>(q, k, tb, out);
}

// Round 3
// 294.326 us; speedup vs baseline: 1.0852x; 1.0493x over previous
//
#include <hip/hip_runtime.h>

#define Bb_ 4
#define Hh_ 16
#define Ss_ 1024
#define DH 64
#define MAXLEN 2048
#define BH (Bb_*Hh_)
#define LDST 72   // 64 + 8 pad (bf16 elems)
#define SW 132    // fp32 epilogue scratch stride (128 + 4 pad words, slow path)

typedef __attribute__((ext_vector_type(8))) short short8;
typedef __attribute__((ext_vector_type(4))) float floatx4;
typedef __attribute__((ext_vector_type(4))) unsigned short ushort4v;

static __device__ __forceinline__ unsigned short f2bf(float f) {
    unsigned int u = __builtin_bit_cast(unsigned int, f);
    u = (u + 0x7fffu + ((u >> 16) & 1u)) >> 16;   // RNE
    return (unsigned short)u;
}

// Stage a 128x64 fp32 tile (row stride 64) -> bf16 LDS tile (row stride LDST)
static __device__ __forceinline__ void stage_tile(unsigned short* lds,
                                                  const float* __restrict__ g,
                                                  int tid) {
#pragma unroll
    for (int it = 0; it < 8; ++it) {
        int idx = it * 1024 + tid * 4;
        int row = idx >> 6, col = idx & 63;
        const float4 v = *reinterpret_cast<const float4*>(g + row * 64 + col);
        ushort4v o = { f2bf(v.x), f2bf(v.y), f2bf(v.z), f2bf(v.w) };
        *reinterpret_cast<ushort4v*>(lds + row * LDST + col) = o;
    }
}

// R16: R11/R14/R15 (three orthogonal store restructures) all ~138 us kernel
// -> the limit is not per-block layout/scheduling but the GLOBAL instantaneous
// address pattern: 512 blocks streaming 512 separate regions = DRAM row-buffer
// thrash at the memory controller (~2-2.5 TB/s). The fill hits 6.3 TB/s as ONE
// sequential sweep. Fix: the 8 lockstep blocks of a bh write INTERLEAVED rows
// (block j: rows s == j mod 8); at iteration it they jointly cover one
// contiguous 32 KB span sweeping the bh region front-to-back => 64 sequential
// sweeps instead of 512 scattered streams. Stores switched NT -> normal
// (cached), matching the fill's config: per-XCD L2 aggregates the co-located
// spans into sequential writebacks. Slow path (never taken on bench data)
// keeps R15's contiguous-strip form; valid since the vote branch is uniform
// per bh (all 8 blocks compute it bitwise-identically).
__global__ __launch_bounds__(256, 2)
void cope_kernel(const float* __restrict__ q, const float* __restrict__ k,
                 const float* __restrict__ tb, float* __restrict__ out) {
    __shared__ __align__(16) unsigned char smem[73728];
    __shared__ __align__(16) float sh_c[128];
    __shared__ __align__(16) float sh_pr[64];
    __shared__ int shf[4];
    __shared__ __align__(16) float ctx_all[1024];  // slow path only

    unsigned short* Ab = reinterpret_cast<unsigned short*>(smem);          // q tile
    unsigned short* Kb = reinterpret_cast<unsigned short*>(smem + 18432);  // 32-row vote k-tile
    float* scratch = reinterpret_cast<float*>(smem + 18432);               // slow epilogue (33792 B)
    unsigned short* Pb = reinterpret_cast<unsigned short*>(smem + 55296);  // slow: k tiles / emb tiles

    int bx = blockIdx.x;
    // blocks sharing this bh's q/k stream are 64 apart -> same XCD
    int bh = bx & 63, jj = bx >> 6;   // jj in [0,8): row-interleave slot
    int tid = threadIdx.x;
    int lane = tid & 63, w = tid >> 6;
    int lo = lane & 15, quad = lane >> 4;

    const float* kb = k + (size_t)bh * Ss_ * DH;
    const float* qb = q + (size_t)bh * Ss_ * DH;

    const float kSig = -0.18033688011112042f;  // -(1/8)*log2(e)

    // ---------------- Phase 1: global clip vote over ALL 1024 t ----------
    {   // stage k rows [992,1024) -> Kb (32 x 64)
        const float* ktop = kb + (size_t)992 * DH;
#pragma unroll
        for (int it = 0; it < 2; ++it) {
            int idx = it * 1024 + tid * 4;
            int row = idx >> 6, col = idx & 63;
            const float4 v = *reinterpret_cast<const float4*>(ktop + row * 64 + col);
            ushort4v o = { f2bf(v.x), f2bf(v.y), f2bf(v.z), f2bf(v.w) };
            *reinterpret_cast<ushort4v*>(Kb + row * LDST + col) = o;
        }
    }

    bool ok = true;
    short8 bkr[2][2];
#pragma unroll 1
    for (int qt = 0; qt < 8; ++qt) {
        stage_tile(Ab, qb + (size_t)qt * 128 * DH, tid);
        __syncthreads();
        if (qt == 0) {
#pragma unroll
            for (int j = 0; j < 2; ++j) {
                bkr[j][0] = *reinterpret_cast<const short8*>(
                    &Kb[(j * 16 + lo) * LDST + 0 + quad * 8]);
                bkr[j][1] = *reinterpret_cast<const short8*>(
                    &Kb[(j * 16 + lo) * LDST + 32 + quad * 8]);
            }
        }
        short8 afr[2][2];
#pragma unroll
        for (int i = 0; i < 2; ++i)
#pragma unroll
            for (int k2 = 0; k2 < 2; ++k2)
                afr[i][k2] = *reinterpret_cast<const short8*>(
                    &Ab[(w * 32 + i * 16 + lo) * LDST + k2 * 32 + quad * 8]);

        float ps[2][4];
#pragma unroll
        for (int i = 0; i < 2; ++i)
#pragma unroll
            for (int r = 0; r < 4; ++r) ps[i][r] = 0.f;

#pragma unroll
        for (int j = 0; j < 2; ++j) {
            float tcol = (float)(992 + j * 16 + lo);
#pragma unroll
            for (int i = 0; i < 2; ++i) {
                floatx4 c = {0.f, 0.f, 0.f, 0.f};
                c = __builtin_amdgcn_mfma_f32_16x16x32_bf16(afr[i][0], bkr[j][0], c, 0, 0, 0);
                c = __builtin_amdgcn_mfma_f32_16x16x32_bf16(afr[i][1], bkr[j][1], c, 0, 0, 0);
#pragma unroll
                for (int r = 0; r < 4; ++r) {
                    float e = __builtin_amdgcn_exp2f(c[r] * kSig);
                    float g = __builtin_amdgcn_rcpf(1.0f + e);
                    ps[i][r] = fmaf(g, tcol, ps[i][r]);
                }
            }
        }
#pragma unroll
        for (int i = 0; i < 2; ++i)
#pragma unroll
            for (int r = 0; r < 4; ++r) {
                float v = ps[i][r];
                v += __shfl_xor(v, 1);
                v += __shfl_xor(v, 2);
                v += __shfl_xor(v, 4);
                v += __shfl_xor(v, 8);
                ok = ok && (v >= 4096.0f);
            }
        __syncthreads();
    }

    int wall = __all(ok);
    if (lane == 0) shf[w] = wall;
    __syncthreads();

    if (shf[0] & shf[1] & shf[2] & shf[3]) {
        // ------- FAST PATH: every ctx clips to 2046 exactly (fr = 0) ------
        if (tid < 16) {
            int d0 = tid * 4;
            *reinterpret_cast<float4*>(&sh_pr[d0]) =
                *reinterpret_cast<const float4*>(tb + (size_t)(MAXLEN - 2) * DH + d0);
        }
        __syncthreads();

        // 128 row-dots for rows s == jj (mod 8): 2 threads per row
        int half = tid & 1;
        float ph[32];
#pragma unroll
        for (int d = 0; d < 32; ++d) ph[d] = sh_pr[half * 32 + d];
        {
            int p = tid >> 1;                 // 0..127
            int row = jj + 8 * p;             // this block's p-th row
            const float* qr = qb + (size_t)row * DH + half * 32;
            float s = 0.f;
#pragma unroll
            for (int d = 0; d < 32; d += 4) {
                const float4 qq = *reinterpret_cast<const float4*>(qr + d);
                s += qq.x * ph[d] + qq.y * ph[d + 1] + qq.z * ph[d + 2] +
                     qq.w * ph[d + 3];
            }
            s += __shfl_xor(s, 1);
            if (half == 0) sh_c[p] = s;
        }
        __syncthreads();

        // Interleaved sweep: at iteration it this block writes row 8*it+jj
        // (one full 4KB line-aligned row); the bh's 8 lockstep blocks jointly
        // cover a contiguous 32KB span marching front-to-back => globally 64
        // sequential streams. Normal cached stores (fill-like writeback).
        float* po = out + (size_t)bh * (Ss_ * Ss_) + (size_t)jj * Ss_ + tid * 4;
#pragma unroll 8
        for (int it = 0; it < 128; ++it) {
            float c = sh_c[it];
            floatx4 vv = {c, c, c, c};
            *reinterpret_cast<floatx4*>(po + (size_t)it * 8 * Ss_) = vv;
        }
        return;
    }

    // ================= SLOW PATH (exact; not taken on bench data) =========
    int s0 = jj << 7;   // contiguous 128-row strip per block (uniform branch)
    // 1) exact ctx for ALL 1024 t-rows
#pragma unroll 1
    for (int qt = 0; qt < 8; ++qt) {
        stage_tile(Ab, qb + (size_t)qt * 128 * DH, tid);
        float rp2[2][4];
#pragma unroll
        for (int i = 0; i < 2; ++i)
#pragma unroll
            for (int r = 0; r < 4; ++r) rp2[i][r] = 0.f;
        short8 afr[2][2];
#pragma unroll 1
        for (int kt = 0; kt < 8; ++kt) {
            stage_tile(Pb, kb + (size_t)kt * 128 * DH, tid);
            __syncthreads();
            if (kt == 0) {
#pragma unroll
                for (int i = 0; i < 2; ++i)
#pragma unroll
                    for (int k2 = 0; k2 < 2; ++k2)
                        afr[i][k2] = *reinterpret_cast<const short8*>(
                            &Ab[(w * 32 + i * 16 + lo) * LDST + k2 * 32 + quad * 8]);
            }
            int t0 = kt << 7;
#pragma unroll
            for (int j = 0; j < 8; ++j) {
                short8 b0 = *reinterpret_cast<const short8*>(
                    &Pb[(j * 16 + lo) * LDST + 0 + quad * 8]);
                short8 b1 = *reinterpret_cast<const short8*>(
                    &Pb[(j * 16 + lo) * LDST + 32 + quad * 8]);
                float tcol = (float)(t0 + j * 16 + lo);
#pragma unroll
                for (int i = 0; i < 2; ++i) {
                    floatx4 c = {0.f, 0.f, 0.f, 0.f};
                    c = __builtin_amdgcn_mfma_f32_16x16x32_bf16(afr[i][0], b0, c, 0, 0, 0);
                    c = __builtin_amdgcn_mfma_f32_16x16x32_bf16(afr[i][1], b1, c, 0, 0, 0);
#pragma unroll
                    for (int r = 0; r < 4; ++r) {
                        float e = __builtin_amdgcn_exp2f(c[r] * kSig);
                        float g = __builtin_amdgcn_rcpf(1.0f + e);
                        rp2[i][r] = fmaf(g, tcol, rp2[i][r]);
                    }
                }
            }
            __syncthreads();
        }
#pragma unroll
        for (int i = 0; i < 2; ++i)
#pragma unroll
            for (int r = 0; r < 4; ++r) {
                float v = rp2[i][r];
                v += __shfl_xor(v, 1);
                v += __shfl_xor(v, 2);
                v += __shfl_xor(v, 4);
                v += __shfl_xor(v, 8);
                if (lo == 0) {
                    int lr = qt * 128 + w * 32 + i * 16 + quad * 4 + r;
                    ctx_all[lr] = fminf(fmaxf(v, 0.f), (float)(MAXLEN - 2));
                }
            }
    }
    __syncthreads();

    // 2) GEMM: out rows [s0,s0+128) x all 1024 cols, emb tiles of 128
    stage_tile(Ab, qb + (size_t)s0 * DH, tid);
    __syncthreads();
    short8 mfr[2][2];
#pragma unroll
    for (int i = 0; i < 2; ++i)
#pragma unroll
        for (int k2 = 0; k2 < 2; ++k2)
            mfr[i][k2] = *reinterpret_cast<const short8*>(
                &Ab[(w * 32 + i * 16 + lo) * LDST + k2 * 32 + quad * 8]);

#pragma unroll 1
    for (int kt = 0; kt < 8; ++kt) {
        {   // build 128-row emb tile for t = kt*128 + row
            int rsub = tid >> 4;       // 0..15
            int d0 = (tid & 15) * 4;   // 0..60
#pragma unroll
            for (int pass = 0; pass < 8; ++pass) {
                int row = pass * 16 + rsub;
                float c = ctx_all[kt * 128 + row];
                int fl = (int)c;
                float fr = c - (float)fl;
                int ce = min(fl + 1, MAXLEN - 1);
                const float4 e0 = *reinterpret_cast<const float4*>(tb + fl * DH + d0);
                const float4 e1 = *reinterpret_cast<const float4*>(tb + ce * DH + d0);
                ushort4v o = { f2bf(e0.x + fr * (e1.x - e0.x)),
                               f2bf(e0.y + fr * (e1.y - e0.y)),
                               f2bf(e0.z + fr * (e1.z - e0.z)),
                               f2bf(e0.w + fr * (e1.w - e0.w)) };
                *reinterpret_cast<ushort4v*>(&Pb[row * LDST + d0]) = o;
            }
        }
        __syncthreads();

        short8 bfr[8][2];
#pragma unroll
        for (int j = 0; j < 8; ++j) {
            bfr[j][0] = *reinterpret_cast<const short8*>(
                &Pb[(j * 16 + lo) * LDST + 0 + quad * 8]);
            bfr[j][1] = *reinterpret_cast<const short8*>(
                &Pb[(j * 16 + lo) * LDST + 32 + quad * 8]);
        }

        floatx4 acc[2][8];
#pragma unroll
        for (int i = 0; i < 2; ++i)
#pragma unroll
            for (int j = 0; j < 8; ++j) acc[i][j] = (floatx4){0.f, 0.f, 0.f, 0.f};

#pragma unroll
        for (int j = 0; j < 8; ++j)
#pragma unroll
            for (int i = 0; i < 2; ++i) {
                acc[i][j] = __builtin_amdgcn_mfma_f32_16x16x32_bf16(
                    mfr[i][0], bfr[j][0], acc[i][j], 0, 0, 0);
                acc[i][j] = __builtin_amdgcn_mfma_f32_16x16x32_bf16(
                    mfr[i][1], bfr[j][1], acc[i][j], 0, 0, 0);
            }

        // Epilogue: LDS transpose -> contiguous dwordx4 stores
#pragma unroll
        for (int i = 0; i < 2; ++i) {
            __syncthreads();
#pragma unroll
            for (int j = 0; j < 8; ++j)
#pragma unroll
                for (int r = 0; r < 4; ++r) {
                    int lrow = w * 16 + quad * 4 + r;
                    scratch[lrow * SW + j * 16 + lo] = acc[i][j][r];
                }
            __syncthreads();
#pragma unroll
            for (int it = 0; it < 8; ++it) {
                int flat = it * 1024 + tid * 4;
                int lrow = flat >> 7, col = flat & 127;
                floatx4 vv =
                    *reinterpret_cast<const floatx4*>(&scratch[lrow * SW + col]);
                int grow = (lrow >> 4) * 32 + i * 16 + (lrow & 15);
                *reinterpret_cast<floatx4*>(
                    out + (size_t)(bh * Ss_ + s0 + grow) * Ss_ + kt * 128 + col) = vv;
            }
        }
        __syncthreads();  // Pb/scratch safe for next kt
    }
}

extern "C" void kernel_launch(void* const* d_in, const int* in_sizes, int n_in,
                              void* d_out, int out_size, void* d_ws, size_t ws_size,
                              hipStream_t stream) {
    const float* q  = (const float*)d_in[0];
    const float* k  = (const float*)d_in[1];
    const float* tb = (const float*)d_in[2];
    float* out = (float*)d_out;

    cope_kernel<<<BH * 8, 256, 0, stream>>>(q, k, tb, out);
}

// Round 4
// 291.650 us; speedup vs baseline: 1.0951x; 1.0092x over previous
//
#include <hip/hip_runtime.h>

#define Bb_ 4
#define Hh_ 16
#define Ss_ 1024
#define DH 64
#define MAXLEN 2048
#define BH (Bb_*Hh_)
#define LDST 72   // 64 + 8 pad (bf16 elems)
#define SW 132    // fp32 epilogue scratch stride (fallback kernel)

typedef __attribute__((ext_vector_type(8))) short short8;
typedef __attribute__((ext_vector_type(4))) float floatx4;
typedef __attribute__((ext_vector_type(4))) unsigned short ushort4v;

static __device__ __forceinline__ unsigned short f2bf(float f) {
    unsigned int u = __builtin_bit_cast(unsigned int, f);
    u = (u + 0x7fffu + ((u >> 16) & 1u)) >> 16;   // RNE
    return (unsigned short)u;
}

// Stage a 128x64 fp32 tile (row stride 64) -> bf16 LDS tile (row stride LDST)
static __device__ __forceinline__ void stage_tile(unsigned short* lds,
                                                  const float* __restrict__ g,
                                                  int tid) {
#pragma unroll
    for (int it = 0; it < 8; ++it) {
        int idx = it * 1024 + tid * 4;
        int row = idx >> 6, col = idx & 63;
        const float4 v = *reinterpret_cast<const float4*>(g + row * 64 + col);
        ushort4v o = { f2bf(v.x), f2bf(v.y), f2bf(v.z), f2bf(v.w) };
        *reinterpret_cast<ushort4v*>(lds + row * LDST + col) = o;
    }
}

// ===========================================================================
// R17: two-kernel split.
// Kernel A (vote): block (bh,j) votes on ONLY its 128 ctx rows (one q-tile,
// not eight -> kills the 8x redundant q staging of R14-R16) against the top
// 32 k-rows; writes flags[bh*8+j] (plain store, no atomics/memset needed:
// rewritten every replay before B reads it) and the per-row constants
// c[bh][s] = q[s].tb[2046] (bit-identical arithmetic to R16's dots).
// Kernel B (emit): maximally fill-like pure-store kernel. 1024 blocks,
// dispatch order == address order, contiguous 256 KB/block, ~20 KB LDS ->
// 4 resident blocks/CU, no prior phases => no inter-block drift. This
// isolates the store-BW question from everything else.
// Slow path (any flag 0; never on bench data): B computes its 64 rows
// exactly and self-contained (fp32 ctx over all k, interp, dots).
// ===========================================================================

__global__ __launch_bounds__(256, 2)
void vote_kernel(const float* __restrict__ q, const float* __restrict__ k,
                 const float* __restrict__ tb, int* __restrict__ flags,
                 float* __restrict__ cvals) {
    __shared__ __align__(16) unsigned short Ab[128 * LDST];
    __shared__ __align__(16) unsigned short Kb[32 * LDST];
    __shared__ __align__(16) float sh_pr[64];
    __shared__ int shf[4];

    int bx = blockIdx.x;
    int bh = bx >> 3, j = bx & 7;
    int tid = threadIdx.x;
    int lane = tid & 63, w = tid >> 6;
    int lo = lane & 15, quad = lane >> 4;

    const float* kb = k + (size_t)bh * Ss_ * DH;
    const float* qb = q + (size_t)bh * Ss_ * DH;
    const float kSig = -0.18033688011112042f;  // -(1/8)*log2(e)

    // stage: k rows [992,1024) -> Kb ; own q tile -> Ab ; e2046 -> sh_pr
    {
        const float* ktop = kb + (size_t)992 * DH;
#pragma unroll
        for (int it = 0; it < 2; ++it) {
            int idx = it * 1024 + tid * 4;
            int row = idx >> 6, col = idx & 63;
            const float4 v = *reinterpret_cast<const float4*>(ktop + row * 64 + col);
            ushort4v o = { f2bf(v.x), f2bf(v.y), f2bf(v.z), f2bf(v.w) };
            *reinterpret_cast<ushort4v*>(Kb + row * LDST + col) = o;
        }
    }
    stage_tile(Ab, qb + (size_t)j * 128 * DH, tid);
    if (tid < 16) {
        int d0 = tid * 4;
        *reinterpret_cast<float4*>(&sh_pr[d0]) =
            *reinterpret_cast<const float4*>(tb + (size_t)(MAXLEN - 2) * DH + d0);
    }
    __syncthreads();

    short8 bkr[2][2];
#pragma unroll
    for (int j2 = 0; j2 < 2; ++j2) {
        bkr[j2][0] = *reinterpret_cast<const short8*>(
            &Kb[(j2 * 16 + lo) * LDST + 0 + quad * 8]);
        bkr[j2][1] = *reinterpret_cast<const short8*>(
            &Kb[(j2 * 16 + lo) * LDST + 32 + quad * 8]);
    }
    short8 afr[2][2];
#pragma unroll
    for (int i = 0; i < 2; ++i)
#pragma unroll
        for (int k2 = 0; k2 < 2; ++k2)
            afr[i][k2] = *reinterpret_cast<const short8*>(
                &Ab[(w * 32 + i * 16 + lo) * LDST + k2 * 32 + quad * 8]);

    float ps[2][4];
#pragma unroll
    for (int i = 0; i < 2; ++i)
#pragma unroll
        for (int r = 0; r < 4; ++r) ps[i][r] = 0.f;

#pragma unroll
    for (int j2 = 0; j2 < 2; ++j2) {
        float tcol = (float)(992 + j2 * 16 + lo);
#pragma unroll
        for (int i = 0; i < 2; ++i) {
            floatx4 c = {0.f, 0.f, 0.f, 0.f};
            c = __builtin_amdgcn_mfma_f32_16x16x32_bf16(afr[i][0], bkr[j2][0], c, 0, 0, 0);
            c = __builtin_amdgcn_mfma_f32_16x16x32_bf16(afr[i][1], bkr[j2][1], c, 0, 0, 0);
#pragma unroll
            for (int r = 0; r < 4; ++r) {
                float e = __builtin_amdgcn_exp2f(c[r] * kSig);
                float g = __builtin_amdgcn_rcpf(1.0f + e);
                ps[i][r] = fmaf(g, tcol, ps[i][r]);
            }
        }
    }

    bool ok = true;
#pragma unroll
    for (int i = 0; i < 2; ++i)
#pragma unroll
        for (int r = 0; r < 4; ++r) {
            float v = ps[i][r];
            v += __shfl_xor(v, 1);
            v += __shfl_xor(v, 2);
            v += __shfl_xor(v, 4);
            v += __shfl_xor(v, 8);
            ok = ok && (v >= 4096.0f);   // margin over 2046 vs bf16 error
        }
    int wall = __all(ok);
    if (lane == 0) shf[w] = wall;
    __syncthreads();
    if (tid == 0) flags[bx] = (shf[0] & shf[1] & shf[2] & shf[3]) & 1;

    // per-row constants c = q[row].e2046 (fp32, same arithmetic as R16)
    {
        int half = tid & 1;
        float ph[32];
#pragma unroll
        for (int d = 0; d < 32; ++d) ph[d] = sh_pr[half * 32 + d];
        int row = tid >> 1;
        const float* qr = qb + (size_t)(j * 128 + row) * DH + half * 32;
        float s = 0.f;
#pragma unroll
        for (int d = 0; d < 32; d += 4) {
            const float4 qq = *reinterpret_cast<const float4*>(qr + d);
            s += qq.x * ph[d] + qq.y * ph[d + 1] + qq.z * ph[d + 2] +
                 qq.w * ph[d + 3];
        }
        s += __shfl_xor(s, 1);
        if (half == 0) cvals[(bh << 10) + j * 128 + row] = s;
    }
}

__global__ __launch_bounds__(256, 4)
void emit_kernel(const float* __restrict__ q, const float* __restrict__ k,
                 const float* __restrict__ tb, const int* __restrict__ flags,
                 const float* __restrict__ cvals, float* __restrict__ out) {
    __shared__ __align__(16) float sh[2048 + 2048 + 1024 + 64];
    float* kch   = sh;            // 2048 f: 32x64 k chunk (slow)
    float* embch = sh + 2048;     // 2048 f: 32x64 emb chunk (slow)
    float* ctxv  = sh + 4096;     // 1024 f: ctx (slow)
    float* shc   = sh + 5120;     // 64 f: row constants (fast)

    int bx = blockIdx.x;
    int bh = bx >> 4, m = bx & 15;
    int tid = threadIdx.x;
    const float* qb = q + (size_t)bh * Ss_ * DH;
    const float* kb = k + (size_t)bh * Ss_ * DH;
    const float kSig = -0.18033688011112042f;

    int fsum = 0;
#pragma unroll
    for (int j2 = 0; j2 < 8; ++j2) fsum += flags[bh * 8 + j2];

    int r0 = m * 64;
    float* po = out + ((size_t)bh << 20) + ((size_t)r0 << 10) + tid * 4;

    if (fsum == 8) {
        // ---- FAST: row-constant, contiguous 256 KB sequential stream ----
        if (tid < 64) shc[tid] = cvals[(bh << 10) + r0 + tid];
        __syncthreads();
#pragma unroll 8
        for (int i = 0; i < 64; ++i) {
            float c = shc[i];
            floatx4 vv = {c, c, c, c};
            *reinterpret_cast<floatx4*>(po + (size_t)i * 1024) = vv;
        }
        return;
    }

    // ---- SLOW (exact; not taken on bench data): self-contained ----------
    // 1) ctx[u] for ALL 1024 u, fp32 exact
#pragma unroll 1
    for (int p = 0; p < 4; ++p) {
        int u = p * 256 + tid;
        float4 qr[16];
#pragma unroll
        for (int d = 0; d < 16; ++d)
            qr[d] = *reinterpret_cast<const float4*>(qb + (size_t)u * DH + d * 4);
        float acc = 0.f;
#pragma unroll 1
        for (int ch = 0; ch < 32; ++ch) {
            __syncthreads();
            {
                int idx = tid * 8;
                const float4 a = *reinterpret_cast<const float4*>(
                    kb + (size_t)ch * 32 * DH + idx);
                const float4 b = *reinterpret_cast<const float4*>(
                    kb + (size_t)ch * 32 * DH + idx + 4);
                *reinterpret_cast<float4*>(kch + idx) = a;
                *reinterpret_cast<float4*>(kch + idx + 4) = b;
            }
            __syncthreads();
#pragma unroll
            for (int tt = 0; tt < 32; ++tt) {
                const float* kr = kch + tt * 64;
                float d = 0.f;
#pragma unroll
                for (int e = 0; e < 16; ++e) {
                    const float4 kk = *reinterpret_cast<const float4*>(kr + e * 4);
                    d += qr[e].x * kk.x + qr[e].y * kk.y + qr[e].z * kk.z +
                         qr[e].w * kk.w;
                }
                float ex = __builtin_amdgcn_exp2f(d * kSig);
                float g = __builtin_amdgcn_rcpf(1.f + ex);
                acc = fmaf(g, (float)(ch * 32 + tt), acc);
            }
        }
        ctxv[u] = fminf(fmaxf(acc, 0.f), (float)(MAXLEN - 2));
    }
    __syncthreads();

    // 2) emit 64 rows x 1024 cols in 32-col chunks
#pragma unroll 1
    for (int ch = 0; ch < 32; ++ch) {
        __syncthreads();
        {   // build emb rows t = ch*32 .. +32 (8 elems/thread)
            int tl = tid >> 3;
            int d0 = (tid & 7) * 8;
            float c = ctxv[ch * 32 + tl];
            int fl = (int)c;
            float fr = c - (float)fl;
            int ce = min(fl + 1, MAXLEN - 1);
#pragma unroll
            for (int e = 0; e < 8; ++e) {
                float e0 = tb[fl * DH + d0 + e];
                float e1 = tb[ce * DH + d0 + e];
                embch[tl * 64 + d0 + e] = e0 + fr * (e1 - e0);
            }
        }
        __syncthreads();
        int s = tid >> 2;
        int t0 = (tid & 3) * 8;
        const float* qr = qb + (size_t)(r0 + s) * DH;
#pragma unroll
        for (int tt = 0; tt < 8; ++tt) {
            const float* er = embch + (t0 + tt) * 64;
            float dsum = 0.f;
#pragma unroll
            for (int e = 0; e < 16; ++e) {
                const float4 qq = *reinterpret_cast<const float4*>(qr + e * 4);
                const float4 ee = *reinterpret_cast<const float4*>(er + e * 4);
                dsum += qq.x * ee.x + qq.y * ee.y + qq.z * ee.z + qq.w * ee.w;
            }
            out[((size_t)bh << 20) + (size_t)(r0 + s) * 1024 + ch * 32 + t0 + tt] =
                dsum;
        }
    }
}

// ===========================================================================
// R16 monolithic kernel — retained as fallback when ws_size is too small.
// ===========================================================================
__global__ __launch_bounds__(256, 2)
void cope_kernel(const float* __restrict__ q, const float* __restrict__ k,
                 const float* __restrict__ tb, float* __restrict__ out) {
    __shared__ __align__(16) unsigned char smem[73728];
    __shared__ __align__(16) float sh_c[128];
    __shared__ __align__(16) float sh_pr[64];
    __shared__ int shf[4];
    __shared__ __align__(16) float ctx_all[1024];

    unsigned short* Ab = reinterpret_cast<unsigned short*>(smem);
    unsigned short* Kb = reinterpret_cast<unsigned short*>(smem + 18432);
    float* scratch = reinterpret_cast<float*>(smem + 18432);
    unsigned short* Pb = reinterpret_cast<unsigned short*>(smem + 55296);

    int bx = blockIdx.x;
    int bh = bx & 63, jj = bx >> 6;
    int tid = threadIdx.x;
    int lane = tid & 63, w = tid >> 6;
    int lo = lane & 15, quad = lane >> 4;

    const float* kb = k + (size_t)bh * Ss_ * DH;
    const float* qb = q + (size_t)bh * Ss_ * DH;
    const float kSig = -0.18033688011112042f;

    {
        const float* ktop = kb + (size_t)992 * DH;
#pragma unroll
        for (int it = 0; it < 2; ++it) {
            int idx = it * 1024 + tid * 4;
            int row = idx >> 6, col = idx & 63;
            const float4 v = *reinterpret_cast<const float4*>(ktop + row * 64 + col);
            ushort4v o = { f2bf(v.x), f2bf(v.y), f2bf(v.z), f2bf(v.w) };
            *reinterpret_cast<ushort4v*>(Kb + row * LDST + col) = o;
        }
    }

    bool ok = true;
    short8 bkr[2][2];
#pragma unroll 1
    for (int qt = 0; qt < 8; ++qt) {
        stage_tile(Ab, qb + (size_t)qt * 128 * DH, tid);
        __syncthreads();
        if (qt == 0) {
#pragma unroll
            for (int j = 0; j < 2; ++j) {
                bkr[j][0] = *reinterpret_cast<const short8*>(
                    &Kb[(j * 16 + lo) * LDST + 0 + quad * 8]);
                bkr[j][1] = *reinterpret_cast<const short8*>(
                    &Kb[(j * 16 + lo) * LDST + 32 + quad * 8]);
            }
        }
        short8 afr[2][2];
#pragma unroll
        for (int i = 0; i < 2; ++i)
#pragma unroll
            for (int k2 = 0; k2 < 2; ++k2)
                afr[i][k2] = *reinterpret_cast<const short8*>(
                    &Ab[(w * 32 + i * 16 + lo) * LDST + k2 * 32 + quad * 8]);

        float ps[2][4];
#pragma unroll
        for (int i = 0; i < 2; ++i)
#pragma unroll
            for (int r = 0; r < 4; ++r) ps[i][r] = 0.f;

#pragma unroll
        for (int j = 0; j < 2; ++j) {
            float tcol = (float)(992 + j * 16 + lo);
#pragma unroll
            for (int i = 0; i < 2; ++i) {
                floatx4 c = {0.f, 0.f, 0.f, 0.f};
                c = __builtin_amdgcn_mfma_f32_16x16x32_bf16(afr[i][0], bkr[j][0], c, 0, 0, 0);
                c = __builtin_amdgcn_mfma_f32_16x16x32_bf16(afr[i][1], bkr[j][1], c, 0, 0, 0);
#pragma unroll
                for (int r = 0; r < 4; ++r) {
                    float e = __builtin_amdgcn_exp2f(c[r] * kSig);
                    float g = __builtin_amdgcn_rcpf(1.0f + e);
                    ps[i][r] = fmaf(g, tcol, ps[i][r]);
                }
            }
        }
#pragma unroll
        for (int i = 0; i < 2; ++i)
#pragma unroll
            for (int r = 0; r < 4; ++r) {
                float v = ps[i][r];
                v += __shfl_xor(v, 1);
                v += __shfl_xor(v, 2);
                v += __shfl_xor(v, 4);
                v += __shfl_xor(v, 8);
                ok = ok && (v >= 4096.0f);
            }
        __syncthreads();
    }

    int wall = __all(ok);
    if (lane == 0) shf[w] = wall;
    __syncthreads();

    if (shf[0] & shf[1] & shf[2] & shf[3]) {
        if (tid < 16) {
            int d0 = tid * 4;
            *reinterpret_cast<float4*>(&sh_pr[d0]) =
                *reinterpret_cast<const float4*>(tb + (size_t)(MAXLEN - 2) * DH + d0);
        }
        __syncthreads();
        int half = tid & 1;
        float ph[32];
#pragma unroll
        for (int d = 0; d < 32; ++d) ph[d] = sh_pr[half * 32 + d];
        {
            int p = tid >> 1;
            int row = jj + 8 * p;
            const float* qr = qb + (size_t)row * DH + half * 32;
            float s = 0.f;
#pragma unroll
            for (int d = 0; d < 32; d += 4) {
                const float4 qq = *reinterpret_cast<const float4*>(qr + d);
                s += qq.x * ph[d] + qq.y * ph[d + 1] + qq.z * ph[d + 2] +
                     qq.w * ph[d + 3];
            }
            s += __shfl_xor(s, 1);
            if (half == 0) sh_c[p] = s;
        }
        __syncthreads();
        float* po = out + (size_t)bh * (Ss_ * Ss_) + (size_t)jj * Ss_ + tid * 4;
#pragma unroll 8
        for (int it = 0; it < 128; ++it) {
            float c = sh_c[it];
            floatx4 vv = {c, c, c, c};
            *reinterpret_cast<floatx4*>(po + (size_t)it * 8 * Ss_) = vv;
        }
        return;
    }

    int s0 = jj << 7;
#pragma unroll 1
    for (int qt = 0; qt < 8; ++qt) {
        stage_tile(Ab, qb + (size_t)qt * 128 * DH, tid);
        float rp2[2][4];
#pragma unroll
        for (int i = 0; i < 2; ++i)
#pragma unroll
            for (int r = 0; r < 4; ++r) rp2[i][r] = 0.f;
        short8 afr[2][2];
#pragma unroll 1
        for (int kt = 0; kt < 8; ++kt) {
            stage_tile(Pb, kb + (size_t)kt * 128 * DH, tid);
            __syncthreads();
            if (kt == 0) {
#pragma unroll
                for (int i = 0; i < 2; ++i)
#pragma unroll
                    for (int k2 = 0; k2 < 2; ++k2)
                        afr[i][k2] = *reinterpret_cast<const short8*>(
                            &Ab[(w * 32 + i * 16 + lo) * LDST + k2 * 32 + quad * 8]);
            }
            int t0 = kt << 7;
#pragma unroll
            for (int j = 0; j < 8; ++j) {
                short8 b0 = *reinterpret_cast<const short8*>(
                    &Pb[(j * 16 + lo) * LDST + 0 + quad * 8]);
                short8 b1 = *reinterpret_cast<const short8*>(
                    &Pb[(j * 16 + lo) * LDST + 32 + quad * 8]);
                float tcol = (float)(t0 + j * 16 + lo);
#pragma unroll
                for (int i = 0; i < 2; ++i) {
                    floatx4 c = {0.f, 0.f, 0.f, 0.f};
                    c = __builtin_amdgcn_mfma_f32_16x16x32_bf16(afr[i][0], b0, c, 0, 0, 0);
                    c = __builtin_amdgcn_mfma_f32_16x16x32_bf16(afr[i][1], b1, c, 0, 0, 0);
#pragma unroll
                    for (int r = 0; r < 4; ++r) {
                        float e = __builtin_amdgcn_exp2f(c[r] * kSig);
                        float g = __builtin_amdgcn_rcpf(1.0f + e);
                        rp2[i][r] = fmaf(g, tcol, rp2[i][r]);
                    }
                }
            }
            __syncthreads();
        }
#pragma unroll
        for (int i = 0; i < 2; ++i)
#pragma unroll
            for (int r = 0; r < 4; ++r) {
                float v = rp2[i][r];
                v += __shfl_xor(v, 1);
                v += __shfl_xor(v, 2);
                v += __shfl_xor(v, 4);
                v += __shfl_xor(v, 8);
                if (lo == 0) {
                    int lr = qt * 128 + w * 32 + i * 16 + quad * 4 + r;
                    ctx_all[lr] = fminf(fmaxf(v, 0.f), (float)(MAXLEN - 2));
                }
            }
    }
    __syncthreads();

    stage_tile(Ab, qb + (size_t)s0 * DH, tid);
    __syncthreads();
    short8 mfr[2][2];
#pragma unroll
    for (int i = 0; i < 2; ++i)
#pragma unroll
        for (int k2 = 0; k2 < 2; ++k2)
            mfr[i][k2] = *reinterpret_cast<const short8*>(
                &Ab[(w * 32 + i * 16 + lo) * LDST + k2 * 32 + quad * 8]);

#pragma unroll 1
    for (int kt = 0; kt < 8; ++kt) {
        {
            int rsub = tid >> 4;
            int d0 = (tid & 15) * 4;
#pragma unroll
            for (int pass = 0; pass < 8; ++pass) {
                int row = pass * 16 + rsub;
                float c = ctx_all[kt * 128 + row];
                int fl = (int)c;
                float fr = c - (float)fl;
                int ce = min(fl + 1, MAXLEN - 1);
                const float4 e0 = *reinterpret_cast<const float4*>(tb + fl * DH + d0);
                const float4 e1 = *reinterpret_cast<const float4*>(tb + ce * DH + d0);
                ushort4v o = { f2bf(e0.x + fr * (e1.x - e0.x)),
                               f2bf(e0.y + fr * (e1.y - e0.y)),
                               f2bf(e0.z + fr * (e1.z - e0.z)),
                               f2bf(e0.w + fr * (e1.w - e0.w)) };
                *reinterpret_cast<ushort4v*>(&Pb[row * LDST + d0]) = o;
            }
        }
        __syncthreads();

        short8 bfr[8][2];
#pragma unroll
        for (int j = 0; j < 8; ++j) {
            bfr[j][0] = *reinterpret_cast<const short8*>(
                &Pb[(j * 16 + lo) * LDST + 0 + quad * 8]);
            bfr[j][1] = *reinterpret_cast<const short8*>(
                &Pb[(j * 16 + lo) * LDST + 32 + quad * 8]);
        }

        floatx4 acc[2][8];
#pragma unroll
        for (int i = 0; i < 2; ++i)
#pragma unroll
            for (int j = 0; j < 8; ++j) acc[i][j] = (floatx4){0.f, 0.f, 0.f, 0.f};

#pragma unroll
        for (int j = 0; j < 8; ++j)
#pragma unroll
            for (int i = 0; i < 2; ++i) {
                acc[i][j] = __builtin_amdgcn_mfma_f32_16x16x32_bf16(
                    mfr[i][0], bfr[j][0], acc[i][j], 0, 0, 0);
                acc[i][j] = __builtin_amdgcn_mfma_f32_16x16x32_bf16(
                    mfr[i][1], bfr[j][1], acc[i][j], 0, 0, 0);
            }

#pragma unroll
        for (int i = 0; i < 2; ++i) {
            __syncthreads();
#pragma unroll
            for (int j = 0; j < 8; ++j)
#pragma unroll
                for (int r = 0; r < 4; ++r) {
                    int lrow = w * 16 + quad * 4 + r;
                    scratch[lrow * SW + j * 16 + lo] = acc[i][j][r];
                }
            __syncthreads();
#pragma unroll
            for (int it = 0; it < 8; ++it) {
                int flat = it * 1024 + tid * 4;
                int lrow = flat >> 7, col = flat & 127;
                floatx4 vv =
                    *reinterpret_cast<const floatx4*>(&scratch[lrow * SW + col]);
                int grow = (lrow >> 4) * 32 + i * 16 + (lrow & 15);
                *reinterpret_cast<floatx4*>(
                    out + (size_t)(bh * Ss_ + s0 + grow) * Ss_ + kt * 128 + col) = vv;
            }
        }
        __syncthreads();
    }
}

extern "C" void kernel_launch(void* const* d_in, const int* in_sizes, int n_in,
                              void* d_out, int out_size, void* d_ws, size_t ws_size,
                              hipStream_t stream) {
    const float* q  = (const float*)d_in[0];
    const float* k  = (const float*)d_in[1];
    const float* tb = (const float*)d_in[2];
    float* out = (float*)d_out;

    // ws layout: flags int[512] @0 ; cvals float[64*1024] @2048
    if (d_ws != nullptr && ws_size >= 2048 + 64 * 1024 * 4) {
        int* flags = (int*)d_ws;
        float* cvals = (float*)((char*)d_ws + 2048);
        vote_kernel<<<BH * 8, 256, 0, stream>>>(q, k, tb, flags, cvals);
        emit_kernel<<<BH * 16, 256, 0, stream>>>(q, k, tb, flags, cvals, out);
    } else {
        cope_kernel<<<BH * 8, 256, 0, stream>>>(q, k, tb, out);
    }
}